// Round 1
// baseline (474.988 us; speedup 1.0000x reference)
//
#include <hip/hip_runtime.h>
#include <hip/hip_bf16.h>

#define T_TOK 256
#define C_DIM 1024
#define H_DIM 2048
#define E_NUM 8

// workspace layout (bytes)
#define WS_IDX   0
#define WS_CNT   1024
#define WS_LIST  2048                       // 8*256*4 = 8192
#define WS_HBUF  16384                      // 256*2048*4 = 2 MB
#define WS_HSBUF (16384 + 2097152)          // 2 MB
#define WS_YS    (16384 + 2*2097152)        // 1 MB

#define UG_TG 16
#define UG_KC 256
#define DN_TG 16
#define DN_KC 256

__global__ __launch_bounds__(256) void router_kernel(
    const float* __restrict__ x, const float* __restrict__ router,
    int* __restrict__ idx, int* __restrict__ cnt, int* __restrict__ list)
{
    const int t = blockIdx.x;
    const int tid = threadIdx.x;
    float4 xv = reinterpret_cast<const float4*>(x + (size_t)t * C_DIM)[tid];
    float p[E_NUM];
#pragma unroll
    for (int e = 0; e < E_NUM; e++) {
        float4 rv = reinterpret_cast<const float4*>(router + (size_t)e * C_DIM)[tid];
        p[e] = xv.x * rv.x + xv.y * rv.y + xv.z * rv.z + xv.w * rv.w;
    }
#pragma unroll
    for (int e = 0; e < E_NUM; e++) {
#pragma unroll
        for (int off = 32; off >= 1; off >>= 1)
            p[e] += __shfl_down(p[e], off, 64);
    }
    __shared__ float red[E_NUM][4];
    const int lane = tid & 63, wv = tid >> 6;
    if (lane == 0) {
#pragma unroll
        for (int e = 0; e < E_NUM; e++) red[e][wv] = p[e];
    }
    __syncthreads();
    if (tid == 0) {
        float best = -3.4e38f; int bi = 0;
#pragma unroll
        for (int e = 0; e < E_NUM; e++) {
            float v = red[e][0] + red[e][1] + red[e][2] + red[e][3];
            if (v > best) { best = v; bi = e; }
        }
        idx[t] = bi;
        int pos = atomicAdd(&cnt[bi], 1);
        list[bi * T_TOK + pos] = t;
    }
}

// grid: (9 experts [8=shared], H/256 chunks, 16 token-groups), block 256.
// lane = one h-row; 16 tokens staged in LDS; weights streamed float4.
__global__ __launch_bounds__(256) void ug_kernel(
    const float* __restrict__ x, const float* __restrict__ up, const float* __restrict__ gate,
    const float* __restrict__ w_up_s, const float* __restrict__ w_gate_s,
    const int* __restrict__ cnt, const int* __restrict__ list,
    float* __restrict__ hbuf, float* __restrict__ hsbuf)
{
    const int e = blockIdx.x;
    const bool sh = (e == E_NUM);
    const int n = sh ? T_TOK : cnt[e];
    const int g0 = blockIdx.z * UG_TG;
    if (g0 >= n) return;
    const int ng = min(UG_TG, n - g0);
    const int h = blockIdx.y * 256 + threadIdx.x;
    const float* __restrict__ urow = sh ? (w_up_s   + (size_t)h * C_DIM)
                                        : (up   + ((size_t)e * H_DIM + h) * C_DIM);
    const float* __restrict__ grow = sh ? (w_gate_s + (size_t)h * C_DIM)
                                        : (gate + ((size_t)e * H_DIM + h) * C_DIM);
    const int* tl = list + e * T_TOK;
    float* __restrict__ outp = sh ? hsbuf : hbuf;

    __shared__ float xs[UG_TG][UG_KC];
    __shared__ int toks[UG_TG];
    if (threadIdx.x < UG_TG) {
        int t = threadIdx.x;
        toks[t] = (t < ng) ? (sh ? (g0 + t) : tl[g0 + t]) : -1;
    }
    float accu[UG_TG], accg[UG_TG];
#pragma unroll
    for (int t = 0; t < UG_TG; t++) { accu[t] = 0.f; accg[t] = 0.f; }

    for (int kc = 0; kc < C_DIM; kc += UG_KC) {
        __syncthreads();
#pragma unroll
        for (int i = threadIdx.x; i < UG_TG * UG_KC; i += 256) {
            int t = i >> 8, k = i & 255;
            int tok = toks[t];
            xs[t][k] = (tok >= 0) ? x[(size_t)tok * C_DIM + kc + k] : 0.f;
        }
        __syncthreads();
        const float4* u4 = reinterpret_cast<const float4*>(urow + kc);
        const float4* g4 = reinterpret_cast<const float4*>(grow + kc);
#pragma unroll 2
        for (int k4 = 0; k4 < UG_KC / 4; ++k4) {
            float4 wu = u4[k4];
            float4 wg = g4[k4];
#pragma unroll
            for (int t = 0; t < UG_TG; t++) {
                float4 xv = *reinterpret_cast<const float4*>(&xs[t][k4 * 4]);
                accu[t] = fmaf(wu.x, xv.x, fmaf(wu.y, xv.y, fmaf(wu.z, xv.z, fmaf(wu.w, xv.w, accu[t]))));
                accg[t] = fmaf(wg.x, xv.x, fmaf(wg.y, xv.y, fmaf(wg.z, xv.z, fmaf(wg.w, xv.w, accg[t]))));
            }
        }
    }
#pragma unroll
    for (int t = 0; t < UG_TG; t++) {
        if (t < ng) {
            int tok = toks[t];
            float g = accg[t];
            float s = 1.f / (1.f + expf(-g));
            outp[(size_t)tok * H_DIM + h] = (g * s) * accu[t];
        }
    }
}

// grid: (9 experts [8=shared], C/256 chunks, 16 token-groups), block 256.
__global__ __launch_bounds__(256) void down_kernel(
    const float* __restrict__ dwn, const float* __restrict__ w_down_s,
    const float* __restrict__ hbuf, const float* __restrict__ hsbuf,
    const int* __restrict__ cnt, const int* __restrict__ list,
    float* __restrict__ y, float* __restrict__ ysbuf)
{
    const int e = blockIdx.x;
    const bool sh = (e == E_NUM);
    const int n = sh ? T_TOK : cnt[e];
    const int g0 = blockIdx.z * DN_TG;
    if (g0 >= n) return;
    const int ng = min(DN_TG, n - g0);
    const int c = blockIdx.y * 256 + threadIdx.x;
    const float* __restrict__ drow = sh ? (w_down_s + (size_t)c * H_DIM)
                                        : (dwn + ((size_t)e * C_DIM + c) * H_DIM);
    const int* tl = list + e * T_TOK;
    const float* __restrict__ hin = sh ? hsbuf : hbuf;
    float* __restrict__ outp = sh ? ysbuf : y;

    __shared__ float hsm[DN_TG][DN_KC];
    __shared__ int toks[DN_TG];
    if (threadIdx.x < DN_TG) {
        int t = threadIdx.x;
        toks[t] = (t < ng) ? (sh ? (g0 + t) : tl[g0 + t]) : -1;
    }
    float acc[DN_TG];
#pragma unroll
    for (int t = 0; t < DN_TG; t++) acc[t] = 0.f;

    for (int kc = 0; kc < H_DIM; kc += DN_KC) {
        __syncthreads();
#pragma unroll
        for (int i = threadIdx.x; i < DN_TG * DN_KC; i += 256) {
            int t = i >> 8, k = i & 255;
            int tok = toks[t];
            hsm[t][k] = (tok >= 0) ? hin[(size_t)tok * H_DIM + kc + k] : 0.f;
        }
        __syncthreads();
        const float4* d4 = reinterpret_cast<const float4*>(drow + kc);
#pragma unroll 2
        for (int k4 = 0; k4 < DN_KC / 4; ++k4) {
            float4 wd = d4[k4];
#pragma unroll
            for (int t = 0; t < DN_TG; t++) {
                float4 hv = *reinterpret_cast<const float4*>(&hsm[t][k4 * 4]);
                acc[t] = fmaf(wd.x, hv.x, fmaf(wd.y, hv.y, fmaf(wd.z, hv.z, fmaf(wd.w, hv.w, acc[t]))));
            }
        }
    }
#pragma unroll
    for (int t = 0; t < DN_TG; t++) {
        if (t < ng) {
            int tok = toks[t];
            outp[(size_t)tok * C_DIM + c] = acc[t];
        }
    }
}

__global__ __launch_bounds__(256) void add_kernel(float* __restrict__ y, const float* __restrict__ ys)
{
    int i = blockIdx.x * 256 + threadIdx.x;
    float4 a = reinterpret_cast<float4*>(y)[i];
    float4 b = reinterpret_cast<const float4*>(ys)[i];
    a.x += b.x; a.y += b.y; a.z += b.z; a.w += b.w;
    reinterpret_cast<float4*>(y)[i] = a;
}

extern "C" void kernel_launch(void* const* d_in, const int* in_sizes, int n_in,
                              void* d_out, int out_size, void* d_ws, size_t ws_size,
                              hipStream_t stream)
{
    const float* x        = (const float*)d_in[0];
    const float* up       = (const float*)d_in[1];
    const float* gate     = (const float*)d_in[2];
    const float* dwn      = (const float*)d_in[3];
    const float* router   = (const float*)d_in[4];
    const float* w_up_s   = (const float*)d_in[5];
    const float* w_gate_s = (const float*)d_in[6];
    const float* w_down_s = (const float*)d_in[7];

    char* ws = (char*)d_ws;
    int* idx    = (int*)(ws + WS_IDX);
    int* cnt    = (int*)(ws + WS_CNT);
    int* list   = (int*)(ws + WS_LIST);
    float* hbuf  = (float*)(ws + WS_HBUF);
    float* hsbuf = (float*)(ws + WS_HSBUF);
    float* ysbuf = (float*)(ws + WS_YS);
    float* y = (float*)d_out;

    hipMemsetAsync(cnt, 0, E_NUM * sizeof(int), stream);
    router_kernel<<<T_TOK, 256, 0, stream>>>(x, router, idx, cnt, list);
    ug_kernel<<<dim3(E_NUM + 1, H_DIM / 256, 16), 256, 0, stream>>>(
        x, up, gate, w_up_s, w_gate_s, cnt, list, hbuf, hsbuf);
    down_kernel<<<dim3(E_NUM + 1, C_DIM / 256, 16), 256, 0, stream>>>(
        dwn, w_down_s, hbuf, hsbuf, cnt, list, y, ysbuf);
    add_kernel<<<(T_TOK * C_DIM / 4) / 256, 256, 0, stream>>>(y, ysbuf);
}

// Round 2
// 142.417 us; speedup vs baseline: 3.3352x; 3.3352x over previous
//
#include <hip/hip_runtime.h>
#include <hip/hip_bf16.h>

#define T_TOK 256
#define C_DIM 1024
#define H_DIM 2048
#define E_NUM 8

#define BM 32
#define BN 64
#define KC 256

typedef __attribute__((ext_vector_type(4))) float f32x4;
typedef __attribute__((ext_vector_type(8))) short short8;

// workspace layout (bytes)
#define WS_IDX   0
#define WS_CNT   1024
#define WS_LIST  2048                        // 8*256*4 = 8192
#define WS_HBUF  16384                       // 256*2048*2 = 1 MB (bf16)
#define WS_HSBUF (16384 + 1048576)           // 1 MB (bf16)
#define WS_YS    (16384 + 2*1048576)         // 1 MB (f32)

__device__ __forceinline__ ushort f2bf(float f) {
    __hip_bfloat16 h = __float2bfloat16(f);
    return *reinterpret_cast<ushort*>(&h);
}

__device__ __forceinline__ short8 pack8(float4 a, float4 b) {
    short8 s;
    s[0] = (short)f2bf(a.x); s[1] = (short)f2bf(a.y);
    s[2] = (short)f2bf(a.z); s[3] = (short)f2bf(a.w);
    s[4] = (short)f2bf(b.x); s[5] = (short)f2bf(b.y);
    s[6] = (short)f2bf(b.z); s[7] = (short)f2bf(b.w);
    return s;
}

__global__ __launch_bounds__(256) void router_kernel(
    const float* __restrict__ x, const float* __restrict__ router,
    int* __restrict__ idx, int* __restrict__ cnt, int* __restrict__ list)
{
    const int t = blockIdx.x;
    const int tid = threadIdx.x;
    float4 xv = reinterpret_cast<const float4*>(x + (size_t)t * C_DIM)[tid];
    float p[E_NUM];
#pragma unroll
    for (int e = 0; e < E_NUM; e++) {
        float4 rv = reinterpret_cast<const float4*>(router + (size_t)e * C_DIM)[tid];
        p[e] = xv.x * rv.x + xv.y * rv.y + xv.z * rv.z + xv.w * rv.w;
    }
#pragma unroll
    for (int e = 0; e < E_NUM; e++) {
#pragma unroll
        for (int off = 32; off >= 1; off >>= 1)
            p[e] += __shfl_down(p[e], off, 64);
    }
    __shared__ float red[E_NUM][4];
    const int lane = tid & 63, wv = tid >> 6;
    if (lane == 0) {
#pragma unroll
        for (int e = 0; e < E_NUM; e++) red[e][wv] = p[e];
    }
    __syncthreads();
    if (tid == 0) {
        float best = -3.4e38f; int bi = 0;
#pragma unroll
        for (int e = 0; e < E_NUM; e++) {
            float v = red[e][0] + red[e][1] + red[e][2] + red[e][3];
            if (v > best) { best = v; bi = e; }
        }
        idx[t] = bi;
        int pos = atomicAdd(&cnt[bi], 1);
        list[bi * T_TOK + pos] = t;
    }
}

// gathered bf16 MFMA GEMM: h[tok][hcol] = silu(x@gate^T) * (x@up^T)
// grid (9 experts [8=shared], H/BN, 8 token-tiles), block 256 (4 waves)
__global__ __launch_bounds__(256) void ug_mfma(
    const float* __restrict__ x, const float* __restrict__ up, const float* __restrict__ gate,
    const float* __restrict__ w_up_s, const float* __restrict__ w_gate_s,
    const int* __restrict__ cnt, const int* __restrict__ list,
    ushort* __restrict__ hbuf, ushort* __restrict__ hsbuf)
{
    const int e = blockIdx.x;
    const bool sh = (e == E_NUM);
    const int n = sh ? T_TOK : cnt[e];
    const int g0 = blockIdx.z * BM;
    if (g0 >= n) return;

    const int tid = threadIdx.x;
    const int lane = tid & 63, wv = tid >> 6;

    __shared__ ushort As[BM][KC + 8];
    __shared__ int toks_s[BM];
    if (tid < BM) {
        int t = g0 + tid;
        toks_s[tid] = (t < n) ? (sh ? t : list[e * T_TOK + t]) : -1;
    }
    __syncthreads();

    const int hglob = blockIdx.y * BN + wv * 16 + (lane & 15);
    const float* __restrict__ urow = sh ? (w_up_s   + (size_t)hglob * C_DIM)
                                        : (up   + ((size_t)e * H_DIM + hglob) * C_DIM);
    const float* __restrict__ grow = sh ? (w_gate_s + (size_t)hglob * C_DIM)
                                        : (gate + ((size_t)e * H_DIM + hglob) * C_DIM);
    const int klane = (lane >> 4) * 8;

    f32x4 accu0 = {0,0,0,0}, accu1 = {0,0,0,0}, accg0 = {0,0,0,0}, accg1 = {0,0,0,0};

    const int sr = tid & 31;          // staging row
    const int sc = (tid >> 5) * 32;   // staging col base (32 f32 per thread)
    const int stok = toks_s[sr];
    const float* xr = (stok >= 0) ? (x + (size_t)stok * C_DIM + sc) : nullptr;

    for (int kc = 0; kc < C_DIM; kc += KC) {
        __syncthreads();
#pragma unroll
        for (int i = 0; i < 4; i++) {
            float4 a = {0,0,0,0}, b = {0,0,0,0};
            if (stok >= 0) {
                a = *reinterpret_cast<const float4*>(xr + kc + i * 8);
                b = *reinterpret_cast<const float4*>(xr + kc + i * 8 + 4);
            }
            *reinterpret_cast<short8*>(&As[sr][sc + i * 8]) = pack8(a, b);
        }
        __syncthreads();

        const ushort* A0 = &As[lane & 15][klane];
        const ushort* A1 = &As[16 + (lane & 15)][klane];
#pragma unroll
        for (int k0 = 0; k0 < KC; k0 += 32) {
            short8 a0 = *reinterpret_cast<const short8*>(A0 + k0);
            short8 a1 = *reinterpret_cast<const short8*>(A1 + k0);
            const float* pu = urow + kc + k0 + klane;
            const float* pg = grow + kc + k0 + klane;
            float4 u0 = *reinterpret_cast<const float4*>(pu);
            float4 u1 = *reinterpret_cast<const float4*>(pu + 4);
            float4 g0v = *reinterpret_cast<const float4*>(pg);
            float4 g1v = *reinterpret_cast<const float4*>(pg + 4);
            short8 bu = pack8(u0, u1);
            short8 bg = pack8(g0v, g1v);
            accu0 = __builtin_amdgcn_mfma_f32_16x16x32_bf16(a0, bu, accu0, 0, 0, 0);
            accu1 = __builtin_amdgcn_mfma_f32_16x16x32_bf16(a1, bu, accu1, 0, 0, 0);
            accg0 = __builtin_amdgcn_mfma_f32_16x16x32_bf16(a0, bg, accg0, 0, 0, 0);
            accg1 = __builtin_amdgcn_mfma_f32_16x16x32_bf16(a1, bg, accg1, 0, 0, 0);
        }
    }

    ushort* __restrict__ outp = sh ? hsbuf : hbuf;
#pragma unroll
    for (int mt = 0; mt < 2; mt++) {
        f32x4 au = mt ? accu1 : accu0;
        f32x4 ag = mt ? accg1 : accg0;
#pragma unroll
        for (int r = 0; r < 4; r++) {
            int m = mt * 16 + (lane >> 4) * 4 + r;
            int tok = toks_s[m];
            if (tok >= 0) {
                float g = ag[r], u = au[r];
                float hv = u * (g / (1.f + __expf(-g)));
                outp[(size_t)tok * H_DIM + hglob] = f2bf(hv);
            }
        }
    }
}

// gathered bf16 MFMA GEMM: y[tok][c] = h @ down^T
// grid (9 experts [8=shared], C/BN, 8 token-tiles), block 256 (4 waves)
__global__ __launch_bounds__(256) void down_mfma(
    const float* __restrict__ dwn, const float* __restrict__ w_down_s,
    const ushort* __restrict__ hbuf, const ushort* __restrict__ hsbuf,
    const int* __restrict__ cnt, const int* __restrict__ list,
    float* __restrict__ y, float* __restrict__ ysbuf)
{
    const int e = blockIdx.x;
    const bool sh = (e == E_NUM);
    const int n = sh ? T_TOK : cnt[e];
    const int g0 = blockIdx.z * BM;
    if (g0 >= n) return;

    const int tid = threadIdx.x;
    const int lane = tid & 63, wv = tid >> 6;

    __shared__ ushort Hs[BM][KC + 8];
    __shared__ int toks_s[BM];
    if (tid < BM) {
        int t = g0 + tid;
        toks_s[tid] = (t < n) ? (sh ? t : list[e * T_TOK + t]) : -1;
    }
    __syncthreads();

    const int cglob = blockIdx.y * BN + wv * 16 + (lane & 15);
    const float* __restrict__ drow = sh ? (w_down_s + (size_t)cglob * H_DIM)
                                        : (dwn + ((size_t)e * C_DIM + cglob) * H_DIM);
    const int klane = (lane >> 4) * 8;
    const ushort* __restrict__ hin = sh ? hsbuf : hbuf;

    f32x4 acc0 = {0,0,0,0}, acc1 = {0,0,0,0};

    const int sr = tid & 31;
    const int sc = (tid >> 5) * 32;
    const int stok = toks_s[sr];
    const ushort* hr = (stok >= 0) ? (hin + (size_t)stok * H_DIM + sc) : nullptr;

    for (int kc = 0; kc < H_DIM; kc += KC) {
        __syncthreads();
#pragma unroll
        for (int i = 0; i < 4; i++) {
            short8 s = {0,0,0,0,0,0,0,0};
            if (stok >= 0) s = *reinterpret_cast<const short8*>(hr + kc + i * 8);
            *reinterpret_cast<short8*>(&Hs[sr][sc + i * 8]) = s;
        }
        __syncthreads();

        const ushort* A0 = &Hs[lane & 15][klane];
        const ushort* A1 = &Hs[16 + (lane & 15)][klane];
#pragma unroll
        for (int k0 = 0; k0 < KC; k0 += 32) {
            short8 a0 = *reinterpret_cast<const short8*>(A0 + k0);
            short8 a1 = *reinterpret_cast<const short8*>(A1 + k0);
            const float* pd = drow + kc + k0 + klane;
            float4 d0 = *reinterpret_cast<const float4*>(pd);
            float4 d1 = *reinterpret_cast<const float4*>(pd + 4);
            short8 bd = pack8(d0, d1);
            acc0 = __builtin_amdgcn_mfma_f32_16x16x32_bf16(a0, bd, acc0, 0, 0, 0);
            acc1 = __builtin_amdgcn_mfma_f32_16x16x32_bf16(a1, bd, acc1, 0, 0, 0);
        }
    }

    float* __restrict__ outp = sh ? ysbuf : y;
#pragma unroll
    for (int mt = 0; mt < 2; mt++) {
        f32x4 a = mt ? acc1 : acc0;
#pragma unroll
        for (int r = 0; r < 4; r++) {
            int m = mt * 16 + (lane >> 4) * 4 + r;
            int tok = toks_s[m];
            if (tok >= 0) outp[(size_t)tok * C_DIM + cglob] = a[r];
        }
    }
}

__global__ __launch_bounds__(256) void add_kernel(float* __restrict__ y, const float* __restrict__ ys)
{
    int i = blockIdx.x * 256 + threadIdx.x;
    float4 a = reinterpret_cast<float4*>(y)[i];
    float4 b = reinterpret_cast<const float4*>(ys)[i];
    a.x += b.x; a.y += b.y; a.z += b.z; a.w += b.w;
    reinterpret_cast<float4*>(y)[i] = a;
}

extern "C" void kernel_launch(void* const* d_in, const int* in_sizes, int n_in,
                              void* d_out, int out_size, void* d_ws, size_t ws_size,
                              hipStream_t stream)
{
    const float* x        = (const float*)d_in[0];
    const float* up       = (const float*)d_in[1];
    const float* gate     = (const float*)d_in[2];
    const float* dwn      = (const float*)d_in[3];
    const float* router   = (const float*)d_in[4];
    const float* w_up_s   = (const float*)d_in[5];
    const float* w_gate_s = (const float*)d_in[6];
    const float* w_down_s = (const float*)d_in[7];

    char* ws = (char*)d_ws;
    int* idx     = (int*)(ws + WS_IDX);
    int* cnt     = (int*)(ws + WS_CNT);
    int* list    = (int*)(ws + WS_LIST);
    ushort* hbuf  = (ushort*)(ws + WS_HBUF);
    ushort* hsbuf = (ushort*)(ws + WS_HSBUF);
    float* ysbuf  = (float*)(ws + WS_YS);
    float* y = (float*)d_out;

    hipMemsetAsync(cnt, 0, E_NUM * sizeof(int), stream);
    router_kernel<<<T_TOK, 256, 0, stream>>>(x, router, idx, cnt, list);
    ug_mfma<<<dim3(E_NUM + 1, H_DIM / BN, 8), 256, 0, stream>>>(
        x, up, gate, w_up_s, w_gate_s, cnt, list, hbuf, hsbuf);
    down_mfma<<<dim3(E_NUM + 1, C_DIM / BN, 8), 256, 0, stream>>>(
        dwn, w_down_s, hbuf, hsbuf, cnt, list, y, ysbuf);
    add_kernel<<<(T_TOK * C_DIM / 4) / 256, 256, 0, stream>>>(y, ysbuf);
}